// Round 1
// baseline (412.209 us; speedup 1.0000x reference)
//
#include <hip/hip_runtime.h>

// out[b,n,k] = |x[b,n,k]| * (1 - w[b,k]*C/(C-1)) + w[b,k] * S[b,n]/(C-1)
// where S[b,n] = sum_c |x[b,n,c]|.  B=64, N=1024, C=1000 (fixed by harness).

constexpr int B = 64;
constexpr int N = 1024;
constexpr int C = 1000;

__global__ __launch_bounds__(256) void wf_kernel(
    const float* __restrict__ x,   // [B,N,C]
    const float* __restrict__ w,   // [B,C]
    float* __restrict__ out)       // [B,N,C]
{
    const int row = blockIdx.x;            // b*N + n
    const int b   = row >> 10;             // N = 1024
    const long long base = (long long)row * C;
    const int tid = threadIdx.x;
    const int c4  = tid * 4;

    __shared__ float s_wave[4];
    __shared__ float s_S;

    float ax = 0.f, ay = 0.f, az = 0.f, aw = 0.f;
    float wx = 0.f, wy = 0.f, wz = 0.f, ww = 0.f;
    if (c4 < C) {
        float4 xv = *reinterpret_cast<const float4*>(x + base + c4);
        ax = fabsf(xv.x); ay = fabsf(xv.y); az = fabsf(xv.z); aw = fabsf(xv.w);
        float4 wv = *reinterpret_cast<const float4*>(w + (long long)b * C + c4);
        wx = wv.x; wy = wv.y; wz = wv.z; ww = wv.w;
    }

    // block reduction: wave shuffle (64 lanes) then LDS combine (4 waves)
    float partial = (ax + ay) + (az + aw);
    #pragma unroll
    for (int off = 32; off > 0; off >>= 1)
        partial += __shfl_down(partial, off, 64);
    const int wave = tid >> 6;
    const int lane = tid & 63;
    if (lane == 0) s_wave[wave] = partial;
    __syncthreads();
    if (tid == 0) s_S = (s_wave[0] + s_wave[1]) + (s_wave[2] + s_wave[3]);
    __syncthreads();
    const float S = s_S;

    if (c4 < C) {
        constexpr float inv = 1.0f / (float)(C - 1);
        const float Sinv = S * inv;
        float4 o;
        o.x = ax * (1.0f - wx - wx * inv) + wx * Sinv;
        o.y = ay * (1.0f - wy - wy * inv) + wy * Sinv;
        o.z = az * (1.0f - wz - wz * inv) + wz * Sinv;
        o.w = aw * (1.0f - ww - ww * inv) + ww * Sinv;
        *reinterpret_cast<float4*>(out + base + c4) = o;
    }
}

extern "C" void kernel_launch(void* const* d_in, const int* in_sizes, int n_in,
                              void* d_out, int out_size, void* d_ws, size_t ws_size,
                              hipStream_t stream) {
    const float* x = (const float*)d_in[0];   // residual [B,N,C]
    const float* w = (const float*)d_in[1];   // weight   [B,C]
    float* out = (float*)d_out;               // [B,N,C]
    (void)in_sizes; (void)n_in; (void)d_ws; (void)ws_size; (void)out_size;

    wf_kernel<<<B * N, 256, 0, stream>>>(x, w, out);
}